// Round 1
// baseline (962.002 us; speedup 1.0000x reference)
//
#include <hip/hip_runtime.h>

#define SCAN_B 256

// ---------------- degree / norm ----------------
__global__ void k_count(const int* __restrict__ src, const int* __restrict__ dst, int E,
                        int* __restrict__ deg_src, int* __restrict__ cnt_dst) {
  int i = blockIdx.x * blockDim.x + threadIdx.x;
  if (i < E) {
    atomicAdd(&deg_src[src[i]], 1);
    atomicAdd(&cnt_dst[dst[i]], 1);
  }
}

__global__ void k_norm(const int* __restrict__ deg, float* __restrict__ nrm, int N) {
  int i = blockIdx.x * blockDim.x + threadIdx.x;
  if (i < N) {
    float d = (float)deg[i];
    if (d < 1.f) d = 1.f;
    nrm[i] = 1.f / sqrtf(d);
  }
}

// ---------------- CSR build (by dst) ----------------
__global__ void k_scan1(const int* __restrict__ cnt, int* __restrict__ excl,
                        int* __restrict__ partial, int N) {
  __shared__ int s[SCAN_B];
  int t = threadIdx.x;
  int i = blockIdx.x * SCAN_B + t;
  int v = (i < N) ? cnt[i] : 0;
  s[t] = v;
  __syncthreads();
  for (int o = 1; o < SCAN_B; o <<= 1) {
    int x = (t >= o) ? s[t - o] : 0;
    __syncthreads();
    s[t] += x;
    __syncthreads();
  }
  if (i < N) excl[i] = s[t] - v;            // exclusive within block
  if (t == SCAN_B - 1) partial[blockIdx.x] = s[t];
}

__global__ void k_scan2(int* __restrict__ partial, int nb) {
  if (blockIdx.x == 0 && threadIdx.x == 0) {
    int acc = 0;
    for (int b = 0; b < nb; b++) { int v = partial[b]; partial[b] = acc; acc += v; }
  }
}

__global__ void k_scan3(const int* __restrict__ excl, const int* __restrict__ partial,
                        int* __restrict__ row_start, int N, int E) {
  int i = blockIdx.x * blockDim.x + threadIdx.x;
  if (i < N) row_start[i] = excl[i] + partial[i / SCAN_B];
  if (i == 0) row_start[N] = E;
}

__global__ void k_scatter(const int* __restrict__ src, const int* __restrict__ dst, int E,
                          const int* __restrict__ row_start, int* __restrict__ cursor,
                          int* __restrict__ csr) {
  int i = blockIdx.x * blockDim.x + threadIdx.x;
  if (i < E) {
    int d = dst[i];
    int p = atomicAdd(&cursor[d], 1);
    csr[row_start[d] + p] = src[i];
  }
}

// ---------------- GEMM1: X = (feat * norm) @ w1   [N,256]x[256,128] ----------------
__global__ __launch_bounds__(128) void k_gemm1(const float* __restrict__ feat,
                                               const float* __restrict__ nrm,
                                               const float* __restrict__ w,
                                               float* __restrict__ X, int N) {
  __shared__ float sf[16 * 256];  // 16 rows of scaled features (16 KB)
  __shared__ float sw[32 * 128];  // K-chunk of w1 (16 KB)
  const int t = threadIdx.x;      // 128 threads: one output column each
  const int row0 = blockIdx.x * 16;

  for (int i = t; i < 16 * 256; i += 128) {
    int r = i >> 8, c = i & 255, gr = row0 + r;
    sf[i] = (gr < N) ? feat[(size_t)gr * 256 + c] * nrm[gr] : 0.f;
  }
  float acc[16];
#pragma unroll
  for (int r = 0; r < 16; r++) acc[r] = 0.f;

  for (int k0 = 0; k0 < 256; k0 += 32) {
    __syncthreads();
    for (int i = t; i < 32 * 128; i += 128)
      sw[i] = w[(size_t)(k0 + (i >> 7)) * 128 + (i & 127)];
    __syncthreads();
    float wr[32];
#pragma unroll
    for (int k = 0; k < 32; k++) wr[k] = sw[k * 128 + t];
#pragma unroll
    for (int r = 0; r < 16; r++) {
      float a0 = 0.f, a1 = 0.f, a2 = 0.f, a3 = 0.f;
#pragma unroll
      for (int k = 0; k < 32; k += 4) {
        float4 f = *(const float4*)&sf[r * 256 + k0 + k];
        a0 += f.x * wr[k + 0];
        a1 += f.y * wr[k + 1];
        a2 += f.z * wr[k + 2];
        a3 += f.w * wr[k + 3];
      }
      acc[r] += (a0 + a1) + (a2 + a3);
    }
  }
#pragma unroll
  for (int r = 0; r < 16; r++) {
    int gr = row0 + r;
    if (gr < N) X[(size_t)gr * 128 + t] = acc[r];
  }
}

// ---------------- Edge aggregation (CSR gather-sum), optional fused epilogue ----------------
// fused=1: Out[d,t] = relu(sum*nrm[d] + bias[t]) * nrm[d]   (conv1 epilogue, pre-scaled for conv2)
// fused=0: Out[d,t] = sum                                    (raw, conv2 pre-GEMM)
__global__ __launch_bounds__(128) void k_agg(const float* __restrict__ Xin,
                                             const int* __restrict__ rs,
                                             const int* __restrict__ csr,
                                             const float* __restrict__ nrm,
                                             const float* __restrict__ bias,
                                             float* __restrict__ Out, int N, int fused) {
  int d = blockIdx.x;
  if (d >= N) return;
  int t = threadIdx.x;  // 128: one feature each
  int s0 = rs[d], s1 = rs[d + 1];
  float acc = 0.f;
  int j = s0;
  for (; j + 4 <= s1; j += 4) {
    int i0 = csr[j], i1 = csr[j + 1], i2 = csr[j + 2], i3 = csr[j + 3];
    acc += Xin[(size_t)i0 * 128 + t] + Xin[(size_t)i1 * 128 + t] +
           Xin[(size_t)i2 * 128 + t] + Xin[(size_t)i3 * 128 + t];
  }
  for (; j < s1; j++) acc += Xin[(size_t)csr[j] * 128 + t];
  if (fused) {
    float nv = nrm[d];
    float h = acc * nv + bias[t];
    h = h > 0.f ? h : 0.f;
    Out[(size_t)d * 128 + t] = h * nv;
  } else {
    Out[(size_t)d * 128 + t] = acc;
  }
}

// ---------------- GEMM2 (+epilogue) + GEMM3 fused ----------------
// h2 = relu((Agg2 @ w2) * nrm + b2);  out = h2 @ w3^T + b3 ; write twice (tuple)
__global__ __launch_bounds__(128) void k_gemm23(const float* __restrict__ Agg2,
                                                const float* __restrict__ nrm,
                                                const float* __restrict__ w2,
                                                const float* __restrict__ b2,
                                                const float* __restrict__ w3,
                                                const float* __restrict__ b3,
                                                float* __restrict__ out, int N) {
  __shared__ float sf[16 * 128];  // 16 rows of Agg2 (8 KB)
  __shared__ float sw[32 * 128];  // K-chunk of w2 (16 KB)
  __shared__ float sh[16 * 128];  // h2 rows (8 KB)
  const int t = threadIdx.x;
  const int row0 = blockIdx.x * 16;

  for (int i = t; i < 16 * 128; i += 128) {
    int r = i >> 7, c = i & 127, gr = row0 + r;
    sf[i] = (gr < N) ? Agg2[(size_t)gr * 128 + c] : 0.f;
  }
  float acc[16];
#pragma unroll
  for (int r = 0; r < 16; r++) acc[r] = 0.f;

  for (int k0 = 0; k0 < 128; k0 += 32) {
    __syncthreads();
    for (int i = t; i < 32 * 128; i += 128)
      sw[i] = w2[(size_t)(k0 + (i >> 7)) * 128 + (i & 127)];
    __syncthreads();
    float wr[32];
#pragma unroll
    for (int k = 0; k < 32; k++) wr[k] = sw[k * 128 + t];
#pragma unroll
    for (int r = 0; r < 16; r++) {
      float a0 = 0.f, a1 = 0.f, a2 = 0.f, a3 = 0.f;
#pragma unroll
      for (int k = 0; k < 32; k += 4) {
        float4 f = *(const float4*)&sf[r * 128 + k0 + k];
        a0 += f.x * wr[k + 0];
        a1 += f.y * wr[k + 1];
        a2 += f.z * wr[k + 2];
        a3 += f.w * wr[k + 3];
      }
      acc[r] += (a0 + a1) + (a2 + a3);
    }
  }
  __syncthreads();
#pragma unroll
  for (int r = 0; r < 16; r++) {
    int gr = row0 + r;
    float nv = (gr < N) ? nrm[gr] : 0.f;
    float h = acc[r] * nv + b2[t];
    h = h > 0.f ? h : 0.f;
    sh[r * 128 + t] = h;
  }
  __syncthreads();
  // final linear: 16 rows x 16 outputs = 256 work items on 128 threads
  for (int i = t; i < 16 * 16; i += 128) {
    int r = i >> 4, o = i & 15;
    int gr = row0 + r;
    if (gr >= N) continue;
    const float* hr = &sh[r * 128];
    const float* w3r = &w3[(size_t)o * 128];
    float s = 0.f;
#pragma unroll 8
    for (int k = 0; k < 128; k++) s += hr[k] * w3r[k];
    float v = s + b3[o];
    out[(size_t)gr * 16 + o] = v;
    out[(size_t)(N + gr) * 16 + o] = v;  // tuple duplicate
  }
}

// ---------------- launch ----------------
extern "C" void kernel_launch(void* const* d_in, const int* in_sizes, int n_in,
                              void* d_out, int out_size, void* d_ws, size_t ws_size,
                              hipStream_t stream) {
  const int N = in_sizes[0];
  const int E = in_sizes[1] / 2;

  const int* e_sub = (const int*)d_in[1];
  const int* src = e_sub;
  const int* dst = e_sub + E;
  const float* feat = (const float*)d_in[3];
  const float* w1 = (const float*)d_in[4];
  const float* b1 = (const float*)d_in[5];
  const float* w2 = (const float*)d_in[6];
  const float* b2 = (const float*)d_in[7];
  const float* w3 = (const float*)d_in[8];
  const float* b3 = (const float*)d_in[9];
  float* out = (float*)d_out;

  // workspace carve-up (256B aligned)
  char* p = (char*)d_ws;
  auto alloc = [&](size_t bytes) { void* r = (void*)p; p += (bytes + 255) & ~(size_t)255; return r; };
  int* deg_src = (int*)alloc((size_t)N * 4);
  int* cnt_dst = (int*)alloc((size_t)N * 4);
  int* excl = (int*)alloc((size_t)N * 4);
  int* partial = (int*)alloc(4096);
  int* row_start = (int*)alloc((size_t)(N + 1) * 4);
  int* cursor = (int*)alloc((size_t)N * 4);
  int* csr = (int*)alloc((size_t)E * 4);
  float* nrm = (float*)alloc((size_t)N * 4);
  float* bufX = (float*)alloc((size_t)N * 128 * 4);  // X, later reused as Agg2
  float* bufH = (float*)alloc((size_t)N * 128 * 4);  // H1n

  hipMemsetAsync(deg_src, 0, (size_t)N * 4, stream);
  hipMemsetAsync(cnt_dst, 0, (size_t)N * 4, stream);
  hipMemsetAsync(cursor, 0, (size_t)N * 4, stream);

  const int NB = (N + SCAN_B - 1) / SCAN_B;
  k_count<<<(E + 255) / 256, 256, 0, stream>>>(src, dst, E, deg_src, cnt_dst);
  k_norm<<<(N + 255) / 256, 256, 0, stream>>>(deg_src, nrm, N);
  k_scan1<<<NB, SCAN_B, 0, stream>>>(cnt_dst, excl, partial, N);
  k_scan2<<<1, 1, 0, stream>>>(partial, NB);
  k_scan3<<<NB, SCAN_B, 0, stream>>>(excl, partial, row_start, N, E);
  k_scatter<<<(E + 255) / 256, 256, 0, stream>>>(src, dst, E, row_start, cursor, csr);

  // conv1: X = (feat*nrm) @ w1
  k_gemm1<<<(N + 15) / 16, 128, 0, stream>>>(feat, nrm, w1, bufX, N);
  // conv1 aggregate + epilogue (relu(sum*nrm+b1)*nrm pre-scaled for conv2)
  k_agg<<<N, 128, 0, stream>>>(bufX, row_start, csr, nrm, b1, bufH, N, 1);
  // conv2 aggregate (raw)
  k_agg<<<N, 128, 0, stream>>>(bufH, row_start, csr, nrm, b1, bufX, N, 0);
  // conv2 GEMM + epilogue + final linear
  k_gemm23<<<(N + 15) / 16, 128, 0, stream>>>(bufX, nrm, w2, b2, w3, b3, out, N);
}

// Round 2
// 751.679 us; speedup vs baseline: 1.2798x; 1.2798x over previous
//
#include <hip/hip_runtime.h>

#define SCAN_B 256
#define AP 40  // padded LDS K-stride (bf16 elems): 80B rows -> 2-way bank aliasing (free)

typedef short bf16x8 __attribute__((ext_vector_type(8)));
typedef float f32x4 __attribute__((ext_vector_type(4)));

static __device__ __forceinline__ ushort f2bf(float f) {
  unsigned u = __float_as_uint(f);
  unsigned r = (u + 0x7fffu + ((u >> 16) & 1u)) >> 16;  // RNE
  return (ushort)r;
}

// ---------------- degree / norm ----------------
__global__ void k_count(const int* __restrict__ src, const int* __restrict__ dst, int E,
                        int* __restrict__ deg_src, int* __restrict__ cnt_dst) {
  int i = blockIdx.x * blockDim.x + threadIdx.x;
  if (i < E) {
    atomicAdd(&deg_src[src[i]], 1);
    atomicAdd(&cnt_dst[dst[i]], 1);
  }
}

__global__ void k_norm(const int* __restrict__ deg, float* __restrict__ nrm, int N) {
  int i = blockIdx.x * blockDim.x + threadIdx.x;
  if (i < N) {
    float d = (float)deg[i];
    if (d < 1.f) d = 1.f;
    nrm[i] = 1.f / sqrtf(d);
  }
}

// ---------------- CSR build (by dst) ----------------
__global__ void k_scan1(const int* __restrict__ cnt, int* __restrict__ excl,
                        int* __restrict__ partial, int N) {
  __shared__ int s[SCAN_B];
  int t = threadIdx.x;
  int i = blockIdx.x * SCAN_B + t;
  int v = (i < N) ? cnt[i] : 0;
  s[t] = v;
  __syncthreads();
  for (int o = 1; o < SCAN_B; o <<= 1) {
    int x = (t >= o) ? s[t - o] : 0;
    __syncthreads();
    s[t] += x;
    __syncthreads();
  }
  if (i < N) excl[i] = s[t] - v;
  if (t == SCAN_B - 1) partial[blockIdx.x] = s[t];
}

__global__ void k_scan2(int* __restrict__ partial, int nb) {
  if (blockIdx.x == 0 && threadIdx.x == 0) {
    int acc = 0;
    for (int b = 0; b < nb; b++) { int v = partial[b]; partial[b] = acc; acc += v; }
  }
}

__global__ void k_scan3(const int* __restrict__ excl, const int* __restrict__ partial,
                        int* __restrict__ row_start, int N, int E) {
  int i = blockIdx.x * blockDim.x + threadIdx.x;
  if (i < N) row_start[i] = excl[i] + partial[i / SCAN_B];
  if (i == 0) row_start[N] = E;
}

__global__ void k_scatter(const int* __restrict__ src, const int* __restrict__ dst, int E,
                          const int* __restrict__ row_start, int* __restrict__ cursor,
                          int* __restrict__ csr) {
  int i = blockIdx.x * blockDim.x + threadIdx.x;
  if (i < E) {
    int d = dst[i];
    int p = atomicAdd(&cursor[d], 1);
    csr[row_start[d] + p] = src[i];
  }
}

// ---------------- prep: fp32 -> bf16 conversions ----------------
__global__ void k_cvt_feat(const float* __restrict__ f, ushort* __restrict__ o, int n4) {
  int stride = gridDim.x * blockDim.x;
  for (int i = blockIdx.x * blockDim.x + threadIdx.x; i < n4; i += stride) {
    float4 v = ((const float4*)f)[i];
    ushort4 u;
    u.x = f2bf(v.x); u.y = f2bf(v.y); u.z = f2bf(v.z); u.w = f2bf(v.w);
    ((ushort4*)o)[i] = u;
  }
}

// w1 [256,128] fp32 row-major -> wT [128 cols][256 k] bf16
__global__ void k_cvt_w1(const float* __restrict__ w, ushort* __restrict__ wT) {
  int i = blockIdx.x * blockDim.x + threadIdx.x;
  if (i < 128 * 256) {
    int c = i >> 8, k = i & 255;
    wT[i] = f2bf(w[k * 128 + c]);
  }
}

// ---------------- GEMM1 (MFMA): X[r,:] = nrm[r] * (featb[r,:] @ w1)  ----------------
// featb [N][256] bf16, wT [128][256] bf16 (col-major over w1), X fp32 [N][128]
__global__ __launch_bounds__(256) void k_gemm1_mfma(const ushort* __restrict__ featb,
                                                    const ushort* __restrict__ wT,
                                                    const float* __restrict__ nrm,
                                                    float* __restrict__ X, int N) {
  __shared__ ushort As[128 * AP];
  __shared__ ushort Bs[128 * AP];
  const int tid = threadIdx.x;
  const int row0 = blockIdx.x * 128;
  const int wv = tid >> 6, lane = tid & 63;
  const int rbase = wv * 32;               // wave's 32-row slice
  const int lr = lane & 15;
  const int kl = (lane >> 4) * 8;

  f32x4 acc[2][8];
#pragma unroll
  for (int mi = 0; mi < 2; mi++)
#pragma unroll
    for (int ni = 0; ni < 8; ni++) acc[mi][ni] = (f32x4)0.f;

  for (int k0 = 0; k0 < 256; k0 += 32) {
    __syncthreads();
#pragma unroll
    for (int j = 0; j < 4; j++) {  // stage A: 128 rows x 32 k
      int e = (tid + j * 256) * 4;
      int r = e >> 5, k = e & 31;
      int gr = row0 + r;
      ushort4 v = make_ushort4(0, 0, 0, 0);
      if (gr < N) v = *(const ushort4*)&featb[(size_t)gr * 256 + k0 + k];
      *(ushort4*)&As[r * AP + k] = v;
    }
#pragma unroll
    for (int j = 0; j < 4; j++) {  // stage B: 128 cols x 32 k
      int e = (tid + j * 256) * 4;
      int c = e >> 5, k = e & 31;
      ushort4 v = *(const ushort4*)&wT[(size_t)c * 256 + k0 + k];
      *(ushort4*)&Bs[c * AP + k] = v;
    }
    __syncthreads();
    bf16x8 af[2], bfr[8];
#pragma unroll
    for (int mi = 0; mi < 2; mi++)
      af[mi] = *(const bf16x8*)&As[(rbase + mi * 16 + lr) * AP + kl];
#pragma unroll
    for (int ni = 0; ni < 8; ni++)
      bfr[ni] = *(const bf16x8*)&Bs[(ni * 16 + lr) * AP + kl];
#pragma unroll
    for (int mi = 0; mi < 2; mi++)
#pragma unroll
      for (int ni = 0; ni < 8; ni++)
        acc[mi][ni] = __builtin_amdgcn_mfma_f32_16x16x32_bf16(af[mi], bfr[ni], acc[mi][ni], 0, 0, 0);
  }
  // epilogue: C/D layout row=(lane>>4)*4+j, col=lane&15 within 16x16 tile
#pragma unroll
  for (int mi = 0; mi < 2; mi++) {
    int rb = row0 + rbase + mi * 16 + (lane >> 4) * 4;
#pragma unroll
    for (int j = 0; j < 4; j++) {
      int gr = rb + j;
      if (gr >= N) continue;
      float nv = nrm[gr];
#pragma unroll
      for (int ni = 0; ni < 8; ni++)
        X[(size_t)gr * 128 + ni * 16 + lr] = acc[mi][ni][j] * nv;
    }
  }
}

// ---------------- Edge aggregation (CSR gather-sum), optional fused epilogue ----------------
__global__ __launch_bounds__(128) void k_agg(const float* __restrict__ Xin,
                                             const int* __restrict__ rs,
                                             const int* __restrict__ csr,
                                             const float* __restrict__ nrm,
                                             const float* __restrict__ bias,
                                             float* __restrict__ Out, int N, int fused) {
  int d = blockIdx.x;
  if (d >= N) return;
  int t = threadIdx.x;
  int s0 = rs[d], s1 = rs[d + 1];
  float acc = 0.f;
  int j = s0;
  for (; j + 4 <= s1; j += 4) {
    int i0 = csr[j], i1 = csr[j + 1], i2 = csr[j + 2], i3 = csr[j + 3];
    acc += Xin[(size_t)i0 * 128 + t] + Xin[(size_t)i1 * 128 + t] +
           Xin[(size_t)i2 * 128 + t] + Xin[(size_t)i3 * 128 + t];
  }
  for (; j < s1; j++) acc += Xin[(size_t)csr[j] * 128 + t];
  if (fused) {
    float nv = nrm[d];
    float h = acc * nv + bias[t];
    h = h > 0.f ? h : 0.f;
    Out[(size_t)d * 128 + t] = h * nv;
  } else {
    Out[(size_t)d * 128 + t] = acc;
  }
}

// ---------------- GEMM2 (+epilogue) + GEMM3 fused (fp32) ----------------
__global__ __launch_bounds__(128) void k_gemm23(const float* __restrict__ Agg2,
                                                const float* __restrict__ nrm,
                                                const float* __restrict__ w2,
                                                const float* __restrict__ b2,
                                                const float* __restrict__ w3,
                                                const float* __restrict__ b3,
                                                float* __restrict__ out, int N) {
  __shared__ float sf[16 * 128];
  __shared__ float sw[32 * 128];
  __shared__ float sh[16 * 128];
  const int t = threadIdx.x;
  const int row0 = blockIdx.x * 16;

  for (int i = t; i < 16 * 128; i += 128) {
    int r = i >> 7, c = i & 127, gr = row0 + r;
    sf[i] = (gr < N) ? Agg2[(size_t)gr * 128 + c] : 0.f;
  }
  float acc[16];
#pragma unroll
  for (int r = 0; r < 16; r++) acc[r] = 0.f;

  for (int k0 = 0; k0 < 128; k0 += 32) {
    __syncthreads();
    for (int i = t; i < 32 * 128; i += 128)
      sw[i] = w2[(size_t)(k0 + (i >> 7)) * 128 + (i & 127)];
    __syncthreads();
    float wr[32];
#pragma unroll
    for (int k = 0; k < 32; k++) wr[k] = sw[k * 128 + t];
#pragma unroll
    for (int r = 0; r < 16; r++) {
      float a0 = 0.f, a1 = 0.f, a2 = 0.f, a3 = 0.f;
#pragma unroll
      for (int k = 0; k < 32; k += 4) {
        float4 f = *(const float4*)&sf[r * 128 + k0 + k];
        a0 += f.x * wr[k + 0];
        a1 += f.y * wr[k + 1];
        a2 += f.z * wr[k + 2];
        a3 += f.w * wr[k + 3];
      }
      acc[r] += (a0 + a1) + (a2 + a3);
    }
  }
  __syncthreads();
#pragma unroll
  for (int r = 0; r < 16; r++) {
    int gr = row0 + r;
    float nv = (gr < N) ? nrm[gr] : 0.f;
    float h = acc[r] * nv + b2[t];
    h = h > 0.f ? h : 0.f;
    sh[r * 128 + t] = h;
  }
  __syncthreads();
  for (int i = t; i < 16 * 16; i += 128) {
    int r = i >> 4, o = i & 15;
    int gr = row0 + r;
    if (gr >= N) continue;
    const float* hr = &sh[r * 128];
    const float* w3r = &w3[(size_t)o * 128];
    float s = 0.f;
#pragma unroll 8
    for (int k = 0; k < 128; k++) s += hr[k] * w3r[k];
    float v = s + b3[o];
    out[(size_t)gr * 16 + o] = v;
    out[(size_t)(N + gr) * 16 + o] = v;
  }
}

// ---------------- launch ----------------
extern "C" void kernel_launch(void* const* d_in, const int* in_sizes, int n_in,
                              void* d_out, int out_size, void* d_ws, size_t ws_size,
                              hipStream_t stream) {
  const int N = in_sizes[0];
  const int E = in_sizes[1] / 2;

  const int* e_sub = (const int*)d_in[1];
  const int* src = e_sub;
  const int* dst = e_sub + E;
  const float* feat = (const float*)d_in[3];
  const float* w1 = (const float*)d_in[4];
  const float* b1 = (const float*)d_in[5];
  const float* w2 = (const float*)d_in[6];
  const float* b2 = (const float*)d_in[7];
  const float* w3 = (const float*)d_in[8];
  const float* b3 = (const float*)d_in[9];
  float* out = (float*)d_out;

  char* p = (char*)d_ws;
  auto alloc = [&](size_t bytes) { void* r = (void*)p; p += (bytes + 255) & ~(size_t)255; return r; };
  int* deg_src = (int*)alloc((size_t)N * 4);
  int* cnt_dst = (int*)alloc((size_t)N * 4);
  int* excl = (int*)alloc((size_t)N * 4);
  int* partial = (int*)alloc(4096);
  int* row_start = (int*)alloc((size_t)(N + 1) * 4);
  int* cursor = (int*)alloc((size_t)N * 4);
  int* csr = (int*)alloc((size_t)E * 4);
  float* nrm = (float*)alloc((size_t)N * 4);
  ushort* w1T = (ushort*)alloc((size_t)128 * 256 * 2);
  float* bufX = (float*)alloc((size_t)N * 128 * 4);  // X, later reused as Agg2
  float* bufH = (float*)alloc((size_t)N * 128 * 4);  // featb (bf16) during gemm1, then H1n
  ushort* featb = (ushort*)bufH;                     // [N][256] bf16 == N*128*4 bytes

  hipMemsetAsync(deg_src, 0, (size_t)N * 4, stream);
  hipMemsetAsync(cnt_dst, 0, (size_t)N * 4, stream);
  hipMemsetAsync(cursor, 0, (size_t)N * 4, stream);

  const int NB = (N + SCAN_B - 1) / SCAN_B;
  k_count<<<(E + 255) / 256, 256, 0, stream>>>(src, dst, E, deg_src, cnt_dst);
  k_norm<<<(N + 255) / 256, 256, 0, stream>>>(deg_src, nrm, N);
  k_scan1<<<NB, SCAN_B, 0, stream>>>(cnt_dst, excl, partial, N);
  k_scan2<<<1, 1, 0, stream>>>(partial, NB);
  k_scan3<<<NB, SCAN_B, 0, stream>>>(excl, partial, row_start, N, E);
  k_scatter<<<(E + 255) / 256, 256, 0, stream>>>(src, dst, E, row_start, cursor, csr);

  // bf16 prep
  k_cvt_feat<<<4096, 256, 0, stream>>>(feat, featb, N * 64);  // N*256/4 float4s
  k_cvt_w1<<<128, 256, 0, stream>>>(w1, w1T);

  // conv1 GEMM (MFMA): X = nrm * (featb @ w1)
  k_gemm1_mfma<<<(N + 127) / 128, 256, 0, stream>>>(featb, w1T, nrm, bufX, N);
  // conv1 aggregate + epilogue (relu(sum*nrm+b1)*nrm, pre-scaled for conv2)
  k_agg<<<N, 128, 0, stream>>>(bufX, row_start, csr, nrm, b1, bufH, N, 1);
  // conv2 aggregate (raw)
  k_agg<<<N, 128, 0, stream>>>(bufH, row_start, csr, nrm, b1, bufX, N, 0);
  // conv2 GEMM + epilogue + final linear
  k_gemm23<<<(N + 15) / 16, 128, 0, stream>>>(bufX, nrm, w2, b2, w3, b3, out, N);
}

// Round 3
// 491.812 us; speedup vs baseline: 1.9560x; 1.5284x over previous
//
#include <hip/hip_runtime.h>

#define SCAN_B 256
#define AP 40    // padded LDS K-stride (bf16): 80B rows -> 2-way bank aliasing (free, m136)
#define H2P 136  // h2 LDS row stride (bf16): 272B -> 2-way

typedef short bf16x8 __attribute__((ext_vector_type(8)));
typedef float f32x4 __attribute__((ext_vector_type(4)));

static __device__ __forceinline__ ushort f2bf(float f) {
  unsigned u = __float_as_uint(f);
  unsigned r = (u + 0x7fffu + ((u >> 16) & 1u)) >> 16;  // RNE
  return (ushort)r;
}
static __device__ __forceinline__ float bflo(unsigned u) { return __uint_as_float(u << 16); }
static __device__ __forceinline__ float bfhi(unsigned u) { return __uint_as_float(u & 0xffff0000u); }
static __device__ __forceinline__ unsigned packbf(float lo, float hi) {
  return (unsigned)f2bf(lo) | ((unsigned)f2bf(hi) << 16);
}

// ---------------- degree / norm ----------------
__global__ void k_count(const int* __restrict__ src, const int* __restrict__ dst, int E,
                        int* __restrict__ deg_src, int* __restrict__ cnt_dst) {
  int i = blockIdx.x * blockDim.x + threadIdx.x;
  if (i < E) {
    atomicAdd(&deg_src[src[i]], 1);
    atomicAdd(&cnt_dst[dst[i]], 1);
  }
}

__global__ void k_norm(const int* __restrict__ deg, float* __restrict__ nrm, int N) {
  int i = blockIdx.x * blockDim.x + threadIdx.x;
  if (i < N) {
    float d = (float)deg[i];
    if (d < 1.f) d = 1.f;
    nrm[i] = 1.f / sqrtf(d);
  }
}

// ---------------- CSR build (by dst) ----------------
__global__ void k_scan1(const int* __restrict__ cnt, int* __restrict__ excl,
                        int* __restrict__ partial, int N) {
  __shared__ int s[SCAN_B];
  int t = threadIdx.x;
  int i = blockIdx.x * SCAN_B + t;
  int v = (i < N) ? cnt[i] : 0;
  s[t] = v;
  __syncthreads();
  for (int o = 1; o < SCAN_B; o <<= 1) {
    int x = (t >= o) ? s[t - o] : 0;
    __syncthreads();
    s[t] += x;
    __syncthreads();
  }
  if (i < N) excl[i] = s[t] - v;
  if (t == SCAN_B - 1) partial[blockIdx.x] = s[t];
}

__global__ void k_scan2(int* __restrict__ partial, int nb) {
  if (blockIdx.x == 0 && threadIdx.x == 0) {
    int acc = 0;
    for (int b = 0; b < nb; b++) { int v = partial[b]; partial[b] = acc; acc += v; }
  }
}

__global__ void k_scan3(const int* __restrict__ excl, const int* __restrict__ partial,
                        int* __restrict__ row_start, int N, int E) {
  int i = blockIdx.x * blockDim.x + threadIdx.x;
  if (i < N) row_start[i] = excl[i] + partial[i / SCAN_B];
  if (i == 0) row_start[N] = E;
}

__global__ void k_scatter(const int* __restrict__ src, const int* __restrict__ dst, int E,
                          const int* __restrict__ row_start, int* __restrict__ cursor,
                          int* __restrict__ csr) {
  int i = blockIdx.x * blockDim.x + threadIdx.x;
  if (i < E) {
    int d = dst[i];
    int p = atomicAdd(&cursor[d], 1);
    csr[row_start[d] + p] = src[i];
  }
}

// ---------------- prep: weight conversions ----------------
// w [K][C] fp32 row-major -> wT [C][K] bf16
__global__ void k_cvt_wT(const float* __restrict__ w, ushort* __restrict__ wT, int K, int C) {
  int i = blockIdx.x * blockDim.x + threadIdx.x;
  if (i < K * C) {
    int c = i / K, k = i - c * K;
    wT[i] = f2bf(w[k * C + c]);
  }
}

__global__ void k_cvt_flat(const float* __restrict__ w, ushort* __restrict__ o, int n) {
  int i = blockIdx.x * blockDim.x + threadIdx.x;
  if (i < n) o[i] = f2bf(w[i]);
}

// ---------------- GEMM1 (MFMA, swapped operands): Xb[r,:] = bf16(nrm[r]*(feat[r,:] @ w1))
// feat fp32 [N][256] (converted during staging), w1T bf16 [128 cols][256 k], Xb bf16 [N][128]
__global__ __launch_bounds__(256) void k_gemm1_mfma(const float* __restrict__ feat,
                                                    const ushort* __restrict__ w1T,
                                                    const float* __restrict__ nrm,
                                                    ushort* __restrict__ Xb, int N) {
  __shared__ ushort As[128 * AP];  // feat rows (B-operand)
  __shared__ ushort Bs[128 * AP];  // w cols   (A-operand)
  const int tid = threadIdx.x;
  const int row0 = blockIdx.x * 128;
  const int wv = tid >> 6, lane = tid & 63;
  const int rbase = wv * 32;
  const int lr = lane & 15;
  const int kl = (lane >> 4) * 8;

  f32x4 acc[8][2];  // [ni: w-col tile][mi: row tile]
#pragma unroll
  for (int ni = 0; ni < 8; ni++)
#pragma unroll
    for (int mi = 0; mi < 2; mi++) acc[ni][mi] = (f32x4)0.f;

  for (int k0 = 0; k0 < 256; k0 += 32) {
    __syncthreads();
#pragma unroll
    for (int j = 0; j < 4; j++) {  // stage A (feat, fp32->bf16): 128 rows x 32 k
      int e = (tid + j * 256) * 4;
      int r = e >> 5, k = e & 31;
      int gr = row0 + r;
      float4 v = make_float4(0.f, 0.f, 0.f, 0.f);
      if (gr < N) v = *(const float4*)&feat[(size_t)gr * 256 + k0 + k];
      ushort4 u;
      u.x = f2bf(v.x); u.y = f2bf(v.y); u.z = f2bf(v.z); u.w = f2bf(v.w);
      *(ushort4*)&As[r * AP + k] = u;
    }
#pragma unroll
    for (int j = 0; j < 4; j++) {  // stage B (w1T): 128 cols x 32 k
      int e = (tid + j * 256) * 4;
      int c = e >> 5, k = e & 31;
      ushort4 v = *(const ushort4*)&w1T[(size_t)c * 256 + k0 + k];
      *(ushort4*)&Bs[c * AP + k] = v;
    }
    __syncthreads();
    bf16x8 bfrag[2], afrag[8];
#pragma unroll
    for (int mi = 0; mi < 2; mi++)
      bfrag[mi] = *(const bf16x8*)&As[(rbase + mi * 16 + lr) * AP + kl];
#pragma unroll
    for (int ni = 0; ni < 8; ni++)
      afrag[ni] = *(const bf16x8*)&Bs[(ni * 16 + lr) * AP + kl];
#pragma unroll
    for (int ni = 0; ni < 8; ni++)
#pragma unroll
      for (int mi = 0; mi < 2; mi++)
        acc[ni][mi] = __builtin_amdgcn_mfma_f32_16x16x32_bf16(afrag[ni], bfrag[mi], acc[ni][mi], 0, 0, 0);
  }
  // D tile: row=(l>>4)*4+j = w-col, col=l&15 = feat row  ->  4 consecutive X cols per lane
#pragma unroll
  for (int mi = 0; mi < 2; mi++) {
    int gr = row0 + rbase + mi * 16 + lr;
    if (gr < N) {
      float nv = nrm[gr];
#pragma unroll
      for (int ni = 0; ni < 8; ni++) {
        int c0 = ni * 16 + (lane >> 4) * 4;
        ushort4 u;
        u.x = f2bf(acc[ni][mi][0] * nv);
        u.y = f2bf(acc[ni][mi][1] * nv);
        u.z = f2bf(acc[ni][mi][2] * nv);
        u.w = f2bf(acc[ni][mi][3] * nv);
        *(ushort4*)&Xb[(size_t)gr * 128 + c0] = u;
      }
    }
  }
}

// ---------------- Edge aggregation (bf16 in, fp32 accum, bf16 out) ----------------
// 1 wave per node; lane holds cols [2*lane, 2*lane+1] packed in a uint.
// fused=1: Out = bf16(relu(sum*nrm+bias)*nrm) ; fused=0: Out = bf16(sum)
__global__ __launch_bounds__(256) void k_agg_bf(const ushort* __restrict__ Xin,
                                                const int* __restrict__ rs,
                                                const int* __restrict__ csr,
                                                const float* __restrict__ nrm,
                                                const float* __restrict__ bias,
                                                ushort* __restrict__ Out, int N, int fused) {
  const int wv = threadIdx.x >> 6, lane = threadIdx.x & 63;
  const int d = blockIdx.x * 4 + wv;
  if (d >= N) return;
  const unsigned* X = (const unsigned*)Xin;
  int s0 = rs[d], s1 = rs[d + 1];
  float a0 = 0.f, a1 = 0.f;
  int j = s0;
  for (; j + 4 <= s1; j += 4) {
    int i0 = csr[j], i1 = csr[j + 1], i2 = csr[j + 2], i3 = csr[j + 3];
    unsigned u0 = X[(size_t)i0 * 64 + lane];
    unsigned u1 = X[(size_t)i1 * 64 + lane];
    unsigned u2 = X[(size_t)i2 * 64 + lane];
    unsigned u3 = X[(size_t)i3 * 64 + lane];
    a0 += (bflo(u0) + bflo(u1)) + (bflo(u2) + bflo(u3));
    a1 += (bfhi(u0) + bfhi(u1)) + (bfhi(u2) + bfhi(u3));
  }
  for (; j < s1; j++) {
    unsigned u = X[(size_t)csr[j] * 64 + lane];
    a0 += bflo(u);
    a1 += bfhi(u);
  }
  unsigned o;
  if (fused) {
    float nv = nrm[d];
    float2 b = *(const float2*)&bias[lane * 2];
    float h0 = fmaxf(a0 * nv + b.x, 0.f) * nv;
    float h1 = fmaxf(a1 * nv + b.y, 0.f) * nv;
    o = packbf(h0, h1);
  } else {
    o = packbf(a0, a1);
  }
  ((unsigned*)Out)[(size_t)d * 64 + lane] = o;
}

// ---------------- GEMM2+3 (MFMA): h2=relu((Agg2@w2)*nrm+b2); out=h2@w3^T+b3 (x2) ----------------
// Agg2 bf16 [N][128], w2T bf16 [128][128], w3b bf16 [16][128]
__global__ __launch_bounds__(256) void k_gemm23_mfma(const ushort* __restrict__ Agg2,
                                                     const float* __restrict__ nrm,
                                                     const ushort* __restrict__ w2T,
                                                     const float* __restrict__ b2,
                                                     const ushort* __restrict__ w3b,
                                                     const float* __restrict__ b3,
                                                     float* __restrict__ out, int N) {
  __shared__ __align__(16) char lds_raw[128 * H2P * 2];  // 34816 B, unioned
  ushort* As = (ushort*)lds_raw;           // [128][AP] agg rows (B-operand)
  ushort* Bs = As + 128 * AP;              // [128][AP] w2 cols  (A-operand)
  ushort* h2s = (ushort*)lds_raw;          // [128][H2P] after K-loop

  const int tid = threadIdx.x;
  const int row0 = blockIdx.x * 128;
  const int wv = tid >> 6, lane = tid & 63;
  const int rbase = wv * 32;
  const int lr = lane & 15;
  const int kl = (lane >> 4) * 8;

  f32x4 acc[8][2];
#pragma unroll
  for (int ni = 0; ni < 8; ni++)
#pragma unroll
    for (int mi = 0; mi < 2; mi++) acc[ni][mi] = (f32x4)0.f;

  for (int k0 = 0; k0 < 128; k0 += 32) {
    __syncthreads();
#pragma unroll
    for (int j = 0; j < 4; j++) {  // stage A (Agg2 bf16): 128 rows x 32 k
      int e = (tid + j * 256) * 4;
      int r = e >> 5, k = e & 31;
      int gr = row0 + r;
      ushort4 v = make_ushort4(0, 0, 0, 0);
      if (gr < N) v = *(const ushort4*)&Agg2[(size_t)gr * 128 + k0 + k];
      *(ushort4*)&As[r * AP + k] = v;
    }
#pragma unroll
    for (int j = 0; j < 4; j++) {  // stage B (w2T)
      int e = (tid + j * 256) * 4;
      int c = e >> 5, k = e & 31;
      ushort4 v = *(const ushort4*)&w2T[(size_t)c * 128 + k0 + k];
      *(ushort4*)&Bs[c * AP + k] = v;
    }
    __syncthreads();
    bf16x8 bfrag[2], afrag[8];
#pragma unroll
    for (int mi = 0; mi < 2; mi++)
      bfrag[mi] = *(const bf16x8*)&As[(rbase + mi * 16 + lr) * AP + kl];
#pragma unroll
    for (int ni = 0; ni < 8; ni++)
      afrag[ni] = *(const bf16x8*)&Bs[(ni * 16 + lr) * AP + kl];
#pragma unroll
    for (int ni = 0; ni < 8; ni++)
#pragma unroll
      for (int mi = 0; mi < 2; mi++)
        acc[ni][mi] = __builtin_amdgcn_mfma_f32_16x16x32_bf16(afrag[ni], bfrag[mi], acc[ni][mi], 0, 0, 0);
  }
  __syncthreads();  // As/Bs dead; h2s aliases them

  // epilogue -> h2 bf16 in LDS (wave-private rows)
#pragma unroll
  for (int mi = 0; mi < 2; mi++) {
    int r = rbase + mi * 16 + lr;
    int gr = row0 + r;
    float nv = (gr < N) ? nrm[gr] : 0.f;
#pragma unroll
    for (int ni = 0; ni < 8; ni++) {
      int c0 = ni * 16 + (lane >> 4) * 4;
      float4 bb = *(const float4*)&b2[c0];
      ushort4 u;
      u.x = f2bf(fmaxf(acc[ni][mi][0] * nv + bb.x, 0.f));
      u.y = f2bf(fmaxf(acc[ni][mi][1] * nv + bb.y, 0.f));
      u.z = f2bf(fmaxf(acc[ni][mi][2] * nv + bb.z, 0.f));
      u.w = f2bf(fmaxf(acc[ni][mi][3] * nv + bb.w, 0.f));
      *(ushort4*)&h2s[r * H2P + c0] = u;
    }
  }
  // GEMM3: A = w3 (16 outputs), B = h2 rows. Wave reads only its own rows.
  f32x4 acc3[2];
  acc3[0] = (f32x4)0.f;
  acc3[1] = (f32x4)0.f;
#pragma unroll
  for (int ks = 0; ks < 4; ks++) {
    bf16x8 a3 = *(const bf16x8*)&w3b[(size_t)lr * 128 + ks * 32 + kl];
#pragma unroll
    for (int mi = 0; mi < 2; mi++) {
      bf16x8 b3f = *(const bf16x8*)&h2s[(rbase + mi * 16 + lr) * H2P + ks * 32 + kl];
      acc3[mi] = __builtin_amdgcn_mfma_f32_16x16x32_bf16(a3, b3f, acc3[mi], 0, 0, 0);
    }
  }
  // D: row=(l>>4)*4+j = output idx o, col=l&15 = node row -> float4 stores
#pragma unroll
  for (int mi = 0; mi < 2; mi++) {
    int gr = row0 + rbase + mi * 16 + lr;
    if (gr < N) {
      int o0 = (lane >> 4) * 4;
      float4 bb = *(const float4*)&b3[o0];
      float4 v;
      v.x = acc3[mi][0] + bb.x;
      v.y = acc3[mi][1] + bb.y;
      v.z = acc3[mi][2] + bb.z;
      v.w = acc3[mi][3] + bb.w;
      *(float4*)&out[(size_t)gr * 16 + o0] = v;
      *(float4*)&out[(size_t)(N + gr) * 16 + o0] = v;
    }
  }
}

// ---------------- launch ----------------
extern "C" void kernel_launch(void* const* d_in, const int* in_sizes, int n_in,
                              void* d_out, int out_size, void* d_ws, size_t ws_size,
                              hipStream_t stream) {
  const int N = in_sizes[0];
  const int E = in_sizes[1] / 2;

  const int* e_sub = (const int*)d_in[1];
  const int* src = e_sub;
  const int* dst = e_sub + E;
  const float* feat = (const float*)d_in[3];
  const float* w1 = (const float*)d_in[4];
  const float* b1 = (const float*)d_in[5];
  const float* w2 = (const float*)d_in[6];
  const float* b2 = (const float*)d_in[7];
  const float* w3 = (const float*)d_in[8];
  const float* b3 = (const float*)d_in[9];
  float* out = (float*)d_out;

  char* p = (char*)d_ws;
  auto alloc = [&](size_t bytes) { void* r = (void*)p; p += (bytes + 255) & ~(size_t)255; return r; };
  int* deg_src = (int*)alloc((size_t)N * 4);
  int* cnt_dst = (int*)alloc((size_t)N * 4);
  int* excl = (int*)alloc((size_t)N * 4);
  int* partial = (int*)alloc(4096);
  int* row_start = (int*)alloc((size_t)(N + 1) * 4);
  int* cursor = (int*)alloc((size_t)N * 4);
  int* csr = (int*)alloc((size_t)E * 4);
  float* nrm = (float*)alloc((size_t)N * 4);
  ushort* w1T = (ushort*)alloc((size_t)128 * 256 * 2);
  ushort* w2T = (ushort*)alloc((size_t)128 * 128 * 2);
  ushort* w3b = (ushort*)alloc((size_t)16 * 128 * 2);
  ushort* Xb = (ushort*)alloc((size_t)N * 128 * 2);    // gemm1 out / agg1 in; later Agg2
  ushort* Hb = (ushort*)alloc((size_t)N * 128 * 2);    // agg1 out (pre-scaled) / agg2 in

  hipMemsetAsync(deg_src, 0, (size_t)N * 4, stream);
  hipMemsetAsync(cnt_dst, 0, (size_t)N * 4, stream);
  hipMemsetAsync(cursor, 0, (size_t)N * 4, stream);

  const int NB = (N + SCAN_B - 1) / SCAN_B;
  k_count<<<(E + 255) / 256, 256, 0, stream>>>(src, dst, E, deg_src, cnt_dst);
  k_norm<<<(N + 255) / 256, 256, 0, stream>>>(deg_src, nrm, N);
  k_scan1<<<NB, SCAN_B, 0, stream>>>(cnt_dst, excl, partial, N);
  k_scan2<<<1, 1, 0, stream>>>(partial, NB);
  k_scan3<<<NB, SCAN_B, 0, stream>>>(excl, partial, row_start, N, E);
  k_scatter<<<(E + 255) / 256, 256, 0, stream>>>(src, dst, E, row_start, cursor, csr);

  k_cvt_wT<<<(256 * 128 + 255) / 256, 256, 0, stream>>>(w1, w1T, 256, 128);
  k_cvt_wT<<<(128 * 128 + 255) / 256, 256, 0, stream>>>(w2, w2T, 128, 128);
  k_cvt_flat<<<8, 256, 0, stream>>>(w3, w3b, 16 * 128);

  // conv1 GEMM: Xb = bf16(nrm * (feat @ w1))
  k_gemm1_mfma<<<(N + 127) / 128, 256, 0, stream>>>(feat, w1T, nrm, Xb, N);
  // conv1 aggregate + epilogue (pre-scaled by nrm for conv2)
  k_agg_bf<<<(N + 3) / 4, 256, 0, stream>>>(Xb, row_start, csr, nrm, b1, Hb, N, 1);
  // conv2 aggregate (raw sums)
  k_agg_bf<<<(N + 3) / 4, 256, 0, stream>>>(Hb, row_start, csr, nrm, b1, Xb, N, 0);
  // conv2 GEMM + epilogue + final linear (tuple dup)
  k_gemm23_mfma<<<(N + 127) / 128, 256, 0, stream>>>(Xb, nrm, w2T, b2, w3b, b3, out, N);
}

// Round 4
// 403.999 us; speedup vs baseline: 2.3812x; 1.2174x over previous
//
#include <hip/hip_runtime.h>

#define SCAN_B 256
#define AP 40    // padded LDS K-stride (bf16): 80B rows -> 2-way bank aliasing (free, m136)
#define H2P 136  // h2 LDS row stride (bf16): 272B -> 2-way
#define HB 240   // histogram blocks (1 per CU at 100KB LDS)

typedef short bf16x8 __attribute__((ext_vector_type(8)));
typedef float f32x4 __attribute__((ext_vector_type(4)));

static __device__ __forceinline__ ushort f2bf(float f) {
  unsigned u = __float_as_uint(f);
  unsigned r = (u + 0x7fffu + ((u >> 16) & 1u)) >> 16;  // RNE
  return (ushort)r;
}
static __device__ __forceinline__ float bflo(unsigned u) { return __uint_as_float(u << 16); }
static __device__ __forceinline__ float bfhi(unsigned u) { return __uint_as_float(u & 0xffff0000u); }
static __device__ __forceinline__ unsigned packbf(float lo, float hi) {
  return (unsigned)f2bf(lo) | ((unsigned)f2bf(hi) << 16);
}

// ---------------- histogram: both endpoints, LDS byte-counters, non-atomic planes ----------------
// planes[ph][b][w]: packed 4x8-bit counts of node-word w by block b (ph 0=src, 1=dst)
__global__ __launch_bounds__(256) void k_hist(const int* __restrict__ src,
                                              const int* __restrict__ dst, int E,
                                              unsigned* __restrict__ planes, int HW) {
  __shared__ unsigned lds[25600];  // 100KB: byte counters for up to 102400 nodes
  const int per = (E + HB - 1) / HB;
  const int s0 = blockIdx.x * per;
  const int s1 = min(E, s0 + per);
#pragma unroll
  for (int ph = 0; ph < 2; ph++) {
    const int* keys = ph ? dst : src;
    for (int i = threadIdx.x; i < HW; i += 256) lds[i] = 0u;
    __syncthreads();
    for (int j = s0 + threadIdx.x; j < s1; j += 256) {
      int k = keys[j];
      atomicAdd(&lds[k >> 2], 1u << ((k & 3) * 8));
    }
    __syncthreads();
    unsigned* out = planes + ((size_t)ph * HB + blockIdx.x) * HW;
    for (int i = threadIdx.x; i < HW; i += 256) out[i] = lds[i];
    __syncthreads();
  }
}

// reduce byte planes -> nrm (from src-degree) and cnt_dst
__global__ void k_hist_reduce(const unsigned* __restrict__ planes, int HW,
                              float* __restrict__ nrm, int* __restrict__ cnt_dst, int N) {
  int t = blockIdx.x * blockDim.x + threadIdx.x;
  if (t >= 2 * HW) return;
  int ph = (t >= HW) ? 1 : 0;
  int w = t - ph * HW;
  const unsigned* base = planes + (size_t)ph * HB * HW + w;
  unsigned c0 = 0, c1 = 0, c2 = 0, c3 = 0;
  for (int b = 0; b < HB; b++) {
    unsigned u = base[(size_t)b * HW];
    c0 += u & 255u;
    c1 += (u >> 8) & 255u;
    c2 += (u >> 16) & 255u;
    c3 += u >> 24;
  }
  int n0 = w * 4;
  unsigned c[4] = {c0, c1, c2, c3};
  if (ph == 0) {
#pragma unroll
    for (int j = 0; j < 4; j++)
      if (n0 + j < N) {
        float d = (float)c[j];
        if (d < 1.f) d = 1.f;
        nrm[n0 + j] = 1.f / sqrtf(d);
      }
  } else {
#pragma unroll
    for (int j = 0; j < 4; j++)
      if (n0 + j < N) cnt_dst[n0 + j] = (int)c[j];
  }
}

// ---------------- CSR build (by dst) ----------------
__global__ void k_scan1(const int* __restrict__ cnt, int* __restrict__ excl,
                        int* __restrict__ partial, int N) {
  __shared__ int s[SCAN_B];
  int t = threadIdx.x;
  int i = blockIdx.x * SCAN_B + t;
  int v = (i < N) ? cnt[i] : 0;
  s[t] = v;
  __syncthreads();
  for (int o = 1; o < SCAN_B; o <<= 1) {
    int x = (t >= o) ? s[t - o] : 0;
    __syncthreads();
    s[t] += x;
    __syncthreads();
  }
  if (i < N) excl[i] = s[t] - v;
  if (t == SCAN_B - 1) partial[blockIdx.x] = s[t];
}

__global__ void k_scan2(int* __restrict__ partial, int nb) {
  if (blockIdx.x == 0 && threadIdx.x == 0) {
    int acc = 0;
    for (int b = 0; b < nb; b++) { int v = partial[b]; partial[b] = acc; acc += v; }
  }
}

__global__ void k_scan3(const int* __restrict__ excl, const int* __restrict__ partial,
                        int* __restrict__ row_start, int N, int E) {
  int i = blockIdx.x * blockDim.x + threadIdx.x;
  if (i < N) row_start[i] = excl[i] + partial[i / SCAN_B];
  if (i == 0) row_start[N] = E;
}

__global__ void k_scatter(const int* __restrict__ src, const int* __restrict__ dst, int E,
                          const int* __restrict__ row_start, int* __restrict__ cursor,
                          int* __restrict__ csr) {
  int i = blockIdx.x * blockDim.x + threadIdx.x;
  if (i < E) {
    int d = dst[i];
    int p = atomicAdd(&cursor[d], 1);
    csr[row_start[d] + p] = src[i];
  }
}

// ---------------- prep: weight conversions ----------------
__global__ void k_cvt_wT(const float* __restrict__ w, ushort* __restrict__ wT, int K, int C) {
  int i = blockIdx.x * blockDim.x + threadIdx.x;
  if (i < K * C) {
    int c = i / K, k = i - c * K;
    wT[i] = f2bf(w[k * C + c]);
  }
}

__global__ void k_cvt_flat(const float* __restrict__ w, ushort* __restrict__ o, int n) {
  int i = blockIdx.x * blockDim.x + threadIdx.x;
  if (i < n) o[i] = f2bf(w[i]);
}

// ---------------- GEMM1 (MFMA, swapped operands): Xb[r,:] = bf16(nrm[r]*(feat[r,:] @ w1))
__global__ __launch_bounds__(256) void k_gemm1_mfma(const float* __restrict__ feat,
                                                    const ushort* __restrict__ w1T,
                                                    const float* __restrict__ nrm,
                                                    ushort* __restrict__ Xb, int N) {
  __shared__ ushort As[128 * AP];  // feat rows (B-operand)
  __shared__ ushort Bs[128 * AP];  // w cols   (A-operand)
  const int tid = threadIdx.x;
  const int row0 = blockIdx.x * 128;
  const int wv = tid >> 6, lane = tid & 63;
  const int rbase = wv * 32;
  const int lr = lane & 15;
  const int kl = (lane >> 4) * 8;

  f32x4 acc[8][2];
#pragma unroll
  for (int ni = 0; ni < 8; ni++)
#pragma unroll
    for (int mi = 0; mi < 2; mi++) acc[ni][mi] = (f32x4)0.f;

  for (int k0 = 0; k0 < 256; k0 += 32) {
    __syncthreads();
#pragma unroll
    for (int j = 0; j < 4; j++) {  // stage A (feat, fp32->bf16): 128 rows x 32 k
      int e = (tid + j * 256) * 4;
      int r = e >> 5, k = e & 31;
      int gr = row0 + r;
      float4 v = make_float4(0.f, 0.f, 0.f, 0.f);
      if (gr < N) v = *(const float4*)&feat[(size_t)gr * 256 + k0 + k];
      ushort4 u;
      u.x = f2bf(v.x); u.y = f2bf(v.y); u.z = f2bf(v.z); u.w = f2bf(v.w);
      *(ushort4*)&As[r * AP + k] = u;
    }
#pragma unroll
    for (int j = 0; j < 4; j++) {  // stage B (w1T): 128 cols x 32 k
      int e = (tid + j * 256) * 4;
      int c = e >> 5, k = e & 31;
      ushort4 v = *(const ushort4*)&w1T[(size_t)c * 256 + k0 + k];
      *(ushort4*)&Bs[c * AP + k] = v;
    }
    __syncthreads();
    bf16x8 bfrag[2], afrag[8];
#pragma unroll
    for (int mi = 0; mi < 2; mi++)
      bfrag[mi] = *(const bf16x8*)&As[(rbase + mi * 16 + lr) * AP + kl];
#pragma unroll
    for (int ni = 0; ni < 8; ni++)
      afrag[ni] = *(const bf16x8*)&Bs[(ni * 16 + lr) * AP + kl];
#pragma unroll
    for (int ni = 0; ni < 8; ni++)
#pragma unroll
      for (int mi = 0; mi < 2; mi++)
        acc[ni][mi] = __builtin_amdgcn_mfma_f32_16x16x32_bf16(afrag[ni], bfrag[mi], acc[ni][mi], 0, 0, 0);
  }
#pragma unroll
  for (int mi = 0; mi < 2; mi++) {
    int gr = row0 + rbase + mi * 16 + lr;
    if (gr < N) {
      float nv = nrm[gr];
#pragma unroll
      for (int ni = 0; ni < 8; ni++) {
        int c0 = ni * 16 + (lane >> 4) * 4;
        ushort4 u;
        u.x = f2bf(acc[ni][mi][0] * nv);
        u.y = f2bf(acc[ni][mi][1] * nv);
        u.z = f2bf(acc[ni][mi][2] * nv);
        u.w = f2bf(acc[ni][mi][3] * nv);
        *(ushort4*)&Xb[(size_t)gr * 128 + c0] = u;
      }
    }
  }
}

// ---------------- Edge aggregation (bf16 in, fp32 accum, bf16 out) ----------------
__global__ __launch_bounds__(256) void k_agg_bf(const ushort* __restrict__ Xin,
                                                const int* __restrict__ rs,
                                                const int* __restrict__ csr,
                                                const float* __restrict__ nrm,
                                                const float* __restrict__ bias,
                                                ushort* __restrict__ Out, int N, int fused) {
  const int wv = threadIdx.x >> 6, lane = threadIdx.x & 63;
  const int d = blockIdx.x * 4 + wv;
  if (d >= N) return;
  const unsigned* X = (const unsigned*)Xin;
  int s0 = rs[d], s1 = rs[d + 1];
  float a0 = 0.f, a1 = 0.f;
  int j = s0;
  for (; j + 4 <= s1; j += 4) {
    int i0 = csr[j], i1 = csr[j + 1], i2 = csr[j + 2], i3 = csr[j + 3];
    unsigned u0 = X[(size_t)i0 * 64 + lane];
    unsigned u1 = X[(size_t)i1 * 64 + lane];
    unsigned u2 = X[(size_t)i2 * 64 + lane];
    unsigned u3 = X[(size_t)i3 * 64 + lane];
    a0 += (bflo(u0) + bflo(u1)) + (bflo(u2) + bflo(u3));
    a1 += (bfhi(u0) + bfhi(u1)) + (bfhi(u2) + bfhi(u3));
  }
  for (; j < s1; j++) {
    unsigned u = X[(size_t)csr[j] * 64 + lane];
    a0 += bflo(u);
    a1 += bfhi(u);
  }
  unsigned o;
  if (fused) {
    float nv = nrm[d];
    float2 b = *(const float2*)&bias[lane * 2];
    float h0 = fmaxf(a0 * nv + b.x, 0.f) * nv;
    float h1 = fmaxf(a1 * nv + b.y, 0.f) * nv;
    o = packbf(h0, h1);
  } else {
    o = packbf(a0, a1);
  }
  ((unsigned*)Out)[(size_t)d * 64 + lane] = o;
}

// ---------------- GEMM2+3 (MFMA): h2=relu((Agg2@w2)*nrm+b2); out=h2@w3^T+b3 (x2) ----------------
__global__ __launch_bounds__(256) void k_gemm23_mfma(const ushort* __restrict__ Agg2,
                                                     const float* __restrict__ nrm,
                                                     const ushort* __restrict__ w2T,
                                                     const float* __restrict__ b2,
                                                     const ushort* __restrict__ w3b,
                                                     const float* __restrict__ b3,
                                                     float* __restrict__ out, int N) {
  __shared__ __align__(16) char lds_raw[128 * H2P * 2];
  ushort* As = (ushort*)lds_raw;
  ushort* Bs = As + 128 * AP;
  ushort* h2s = (ushort*)lds_raw;

  const int tid = threadIdx.x;
  const int row0 = blockIdx.x * 128;
  const int wv = tid >> 6, lane = tid & 63;
  const int rbase = wv * 32;
  const int lr = lane & 15;
  const int kl = (lane >> 4) * 8;

  f32x4 acc[8][2];
#pragma unroll
  for (int ni = 0; ni < 8; ni++)
#pragma unroll
    for (int mi = 0; mi < 2; mi++) acc[ni][mi] = (f32x4)0.f;

  for (int k0 = 0; k0 < 128; k0 += 32) {
    __syncthreads();
#pragma unroll
    for (int j = 0; j < 4; j++) {
      int e = (tid + j * 256) * 4;
      int r = e >> 5, k = e & 31;
      int gr = row0 + r;
      ushort4 v = make_ushort4(0, 0, 0, 0);
      if (gr < N) v = *(const ushort4*)&Agg2[(size_t)gr * 128 + k0 + k];
      *(ushort4*)&As[r * AP + k] = v;
    }
#pragma unroll
    for (int j = 0; j < 4; j++) {
      int e = (tid + j * 256) * 4;
      int c = e >> 5, k = e & 31;
      ushort4 v = *(const ushort4*)&w2T[(size_t)c * 128 + k0 + k];
      *(ushort4*)&Bs[c * AP + k] = v;
    }
    __syncthreads();
    bf16x8 bfrag[2], afrag[8];
#pragma unroll
    for (int mi = 0; mi < 2; mi++)
      bfrag[mi] = *(const bf16x8*)&As[(rbase + mi * 16 + lr) * AP + kl];
#pragma unroll
    for (int ni = 0; ni < 8; ni++)
      afrag[ni] = *(const bf16x8*)&Bs[(ni * 16 + lr) * AP + kl];
#pragma unroll
    for (int ni = 0; ni < 8; ni++)
#pragma unroll
      for (int mi = 0; mi < 2; mi++)
        acc[ni][mi] = __builtin_amdgcn_mfma_f32_16x16x32_bf16(afrag[ni], bfrag[mi], acc[ni][mi], 0, 0, 0);
  }
  __syncthreads();

#pragma unroll
  for (int mi = 0; mi < 2; mi++) {
    int r = rbase + mi * 16 + lr;
    int gr = row0 + r;
    float nv = (gr < N) ? nrm[gr] : 0.f;
#pragma unroll
    for (int ni = 0; ni < 8; ni++) {
      int c0 = ni * 16 + (lane >> 4) * 4;
      float4 bb = *(const float4*)&b2[c0];
      ushort4 u;
      u.x = f2bf(fmaxf(acc[ni][mi][0] * nv + bb.x, 0.f));
      u.y = f2bf(fmaxf(acc[ni][mi][1] * nv + bb.y, 0.f));
      u.z = f2bf(fmaxf(acc[ni][mi][2] * nv + bb.z, 0.f));
      u.w = f2bf(fmaxf(acc[ni][mi][3] * nv + bb.w, 0.f));
      *(ushort4*)&h2s[r * H2P + c0] = u;
    }
  }
  f32x4 acc3[2];
  acc3[0] = (f32x4)0.f;
  acc3[1] = (f32x4)0.f;
#pragma unroll
  for (int ks = 0; ks < 4; ks++) {
    bf16x8 a3 = *(const bf16x8*)&w3b[(size_t)lr * 128 + ks * 32 + kl];
#pragma unroll
    for (int mi = 0; mi < 2; mi++) {
      bf16x8 b3f = *(const bf16x8*)&h2s[(rbase + mi * 16 + lr) * H2P + ks * 32 + kl];
      acc3[mi] = __builtin_amdgcn_mfma_f32_16x16x32_bf16(a3, b3f, acc3[mi], 0, 0, 0);
    }
  }
#pragma unroll
  for (int mi = 0; mi < 2; mi++) {
    int gr = row0 + rbase + mi * 16 + lr;
    if (gr < N) {
      int o0 = (lane >> 4) * 4;
      float4 bb = *(const float4*)&b3[o0];
      float4 v;
      v.x = acc3[mi][0] + bb.x;
      v.y = acc3[mi][1] + bb.y;
      v.z = acc3[mi][2] + bb.z;
      v.w = acc3[mi][3] + bb.w;
      *(float4*)&out[(size_t)gr * 16 + o0] = v;
      *(float4*)&out[(size_t)(N + gr) * 16 + o0] = v;
    }
  }
}

// ---------------- launch ----------------
extern "C" void kernel_launch(void* const* d_in, const int* in_sizes, int n_in,
                              void* d_out, int out_size, void* d_ws, size_t ws_size,
                              hipStream_t stream) {
  const int N = in_sizes[0];
  const int E = in_sizes[1] / 2;
  const int HW = (N + 3) / 4;  // packed byte-counter words (must be <= 25600)

  const int* e_sub = (const int*)d_in[1];
  const int* src = e_sub;
  const int* dst = e_sub + E;
  const float* feat = (const float*)d_in[3];
  const float* w1 = (const float*)d_in[4];
  const float* b1 = (const float*)d_in[5];
  const float* w2 = (const float*)d_in[6];
  const float* b2 = (const float*)d_in[7];
  const float* w3 = (const float*)d_in[8];
  const float* b3 = (const float*)d_in[9];
  float* out = (float*)d_out;

  char* p = (char*)d_ws;
  auto alloc = [&](size_t bytes) { void* r = (void*)p; p += (bytes + 255) & ~(size_t)255; return r; };
  int* cnt_dst = (int*)alloc((size_t)N * 4);
  int* excl = (int*)alloc((size_t)N * 4);
  int* partial = (int*)alloc(4096);
  int* row_start = (int*)alloc((size_t)(N + 1) * 4);
  int* cursor = (int*)alloc((size_t)N * 4);
  int* csr = (int*)alloc((size_t)E * 4);
  float* nrm = (float*)alloc((size_t)N * 4);
  ushort* w1T = (ushort*)alloc((size_t)128 * 256 * 2);
  ushort* w2T = (ushort*)alloc((size_t)128 * 128 * 2);
  ushort* w3b = (ushort*)alloc((size_t)16 * 128 * 2);
  ushort* Xb = (ushort*)alloc((size_t)N * 128 * 2);
  ushort* Hb = (ushort*)alloc((size_t)N * 128 * 2);
  unsigned* planes = (unsigned*)alloc((size_t)2 * HB * HW * 4);  // 48MB for N=100k

  hipMemsetAsync(cursor, 0, (size_t)N * 4, stream);

  const int NB = (N + SCAN_B - 1) / SCAN_B;
  // histogram of src (-> nrm) and dst (-> cnt_dst), atomic-free
  k_hist<<<HB, 256, 0, stream>>>(src, dst, E, planes, HW);
  k_hist_reduce<<<(2 * HW + 255) / 256, 256, 0, stream>>>(planes, HW, nrm, cnt_dst, N);
  // CSR build
  k_scan1<<<NB, SCAN_B, 0, stream>>>(cnt_dst, excl, partial, N);
  k_scan2<<<1, 1, 0, stream>>>(partial, NB);
  k_scan3<<<NB, SCAN_B, 0, stream>>>(excl, partial, row_start, N, E);
  k_scatter<<<(E + 255) / 256, 256, 0, stream>>>(src, dst, E, row_start, cursor, csr);

  k_cvt_wT<<<(256 * 128 + 255) / 256, 256, 0, stream>>>(w1, w1T, 256, 128);
  k_cvt_wT<<<(128 * 128 + 255) / 256, 256, 0, stream>>>(w2, w2T, 128, 128);
  k_cvt_flat<<<8, 256, 0, stream>>>(w3, w3b, 16 * 128);

  k_gemm1_mfma<<<(N + 127) / 128, 256, 0, stream>>>(feat, w1T, nrm, Xb, N);
  k_agg_bf<<<(N + 3) / 4, 256, 0, stream>>>(Xb, row_start, csr, nrm, b1, Hb, N, 1);
  k_agg_bf<<<(N + 3) / 4, 256, 0, stream>>>(Hb, row_start, csr, nrm, b1, Xb, N, 0);
  k_gemm23_mfma<<<(N + 127) / 128, 256, 0, stream>>>(Xb, nrm, w2T, b2, w3b, b3, out, N);
}